// Round 1
// baseline (847.956 us; speedup 1.0000x reference)
//
#include <hip/hip_runtime.h>
#include <hip/hip_bf16.h>

// SpecAttn: out = softmax((x@Wq+bq)(x@Wk+bk)^T / 32) @ (x@Wv+bv) @ Wo + bo
// B=8, S=2048, H=1024. Strategy: bf16 MFMA for all 5 GEMM stages (threshold is
// 2% of max|ref| -> bf16-tolerant), fp32 accumulate, standalone softmax.

typedef __attribute__((ext_vector_type(8))) __bf16 bf16x8;
typedef __attribute__((ext_vector_type(4))) __bf16 bf16x4;
typedef __attribute__((ext_vector_type(4))) float  f32x4;
typedef __attribute__((ext_vector_type(8))) float  f32x8;

__device__ __forceinline__ void gl_lds16(const void* g, void* l) {
    __builtin_amdgcn_global_load_lds(
        (__attribute__((address_space(1))) const void*)g,
        (__attribute__((address_space(3))) void*)l, 16, 0, 0);
}

// ---------------- fp32 -> bf16 convert (x) ----------------
__global__ __launch_bounds__(256) void k_convert(const float* __restrict__ in,
                                                 __bf16* __restrict__ out) {
    const int i = blockIdx.x * 256 + threadIdx.x;   // 8 elems/thread, exact fit
    f32x8 a = *((const f32x8*)in + i);
    bf16x8 o;
#pragma unroll
    for (int j = 0; j < 8; ++j) o[j] = (__bf16)a[j];
    *((bf16x8*)out + i) = o;
}

// ------------- fp32 W[k][n] -> bf16 Wt[n][k] (1024x1024) -------------
__global__ __launch_bounds__(256) void k_transpose_w(const float* __restrict__ W,
                                                     __bf16* __restrict__ Wt) {
    __shared__ float t[64][65];
    const int tid = threadIdx.x;
    const int c4 = (tid & 15) * 4, r0 = tid >> 4;
    const int bx = blockIdx.x * 64, by = blockIdx.y * 64;
#pragma unroll
    for (int p = 0; p < 4; ++p) {
        const int r = r0 + p * 16;
        f32x4 v = *(const f32x4*)(W + (long long)(by + r) * 1024 + bx + c4);
#pragma unroll
        for (int j = 0; j < 4; ++j) t[r][c4 + j] = v[j];
    }
    __syncthreads();
#pragma unroll
    for (int p = 0; p < 4; ++p) {
        const int r = r0 + p * 16;
        bf16x4 o;
#pragma unroll
        for (int j = 0; j < 4; ++j) o[j] = (__bf16)t[c4 + j][r];
        *(bf16x4*)(Wt + (long long)(bx + r) * 1024 + by + c4) = o;
    }
}

// ------------- bf16 V[b][s][h] -> Vt[b][h][s] -------------
__global__ __launch_bounds__(256) void k_transpose_v(const __bf16* __restrict__ V,
                                                     __bf16* __restrict__ Vt) {
    __shared__ __bf16 t[64][65];
    const long long zoff = (long long)blockIdx.z * 2097152;  // 2048*1024
    const __bf16* Vb = V + zoff;
    __bf16* Vtb = Vt + zoff;
    const int tid = threadIdx.x;
    const int c4 = (tid & 15) * 4, r0 = tid >> 4;
    const int bx = blockIdx.x * 64;  // h tile
    const int by = blockIdx.y * 64;  // s tile
#pragma unroll
    for (int p = 0; p < 4; ++p) {
        const int r = r0 + p * 16;
        bf16x4 v = *(const bf16x4*)(Vb + (long long)(by + r) * 1024 + bx + c4);
#pragma unroll
        for (int j = 0; j < 4; ++j) t[r][c4 + j] = v[j];
    }
    __syncthreads();
#pragma unroll
    for (int p = 0; p < 4; ++p) {
        const int r = r0 + p * 16;
        bf16x4 o;
#pragma unroll
        for (int j = 0; j < 4; ++j) o[j] = t[c4 + j][r];
        *(bf16x4*)(Vtb + (long long)(bx + r) * 2048 + by + c4) = o;
    }
}

// ------------- row softmax over 2048 cols, in place, bf16 -------------
__global__ __launch_bounds__(256) void k_softmax(__bf16* __restrict__ E) {
    __bf16* p = E + (long long)blockIdx.x * 2048;
    const int tid = threadIdx.x, l = tid & 63, w = tid >> 6;
    bf16x8 vb = *((const bf16x8*)p + tid);
    float v[8];
#pragma unroll
    for (int i = 0; i < 8; ++i) v[i] = (float)vb[i];
    float m = v[0];
#pragma unroll
    for (int i = 1; i < 8; ++i) m = fmaxf(m, v[i]);
    for (int off = 32; off > 0; off >>= 1) m = fmaxf(m, __shfl_xor(m, off));
    __shared__ float redm[4], reds[4];
    if (l == 0) redm[w] = m;
    __syncthreads();
    m = fmaxf(fmaxf(redm[0], redm[1]), fmaxf(redm[2], redm[3]));
    float e[8], s = 0.f;
#pragma unroll
    for (int i = 0; i < 8; ++i) { e[i] = __expf(v[i] - m); s += e[i]; }
    for (int off = 32; off > 0; off >>= 1) s += __shfl_xor(s, off);
    if (l == 0) reds[w] = s;
    __syncthreads();
    s = reds[0] + reds[1] + reds[2] + reds[3];
    const float inv = 1.0f / s;
    bf16x8 o;
#pragma unroll
    for (int i = 0; i < 8; ++i) o[i] = (__bf16)(e[i] * inv);
    *((bf16x8*)p + tid) = o;
}

// ------------- GEMM: C[z] = A[z] @ Bt[z]^T * scale (+bias) -------------
// A: [M][K] bf16 row-major; Bt: [N][K] bf16 row-major; tiles 128x128, BK=32.
// LDS layout K-major [kq][row][8] so frag reads are single ds_read_b128,
// conflict-free; chunk order matches global_load_lds "base + lane*16" rule.
template <bool OUT_F32, bool HAS_BIAS>
__global__ __launch_bounds__(256) void gemm_bt(
    const __bf16* __restrict__ A, const __bf16* __restrict__ Bt,
    const float* __restrict__ bias, void* __restrict__ Cout,
    int M, int N, int K, float scale,
    long long sA, long long sB, long long sC) {
    __shared__ __align__(16) __bf16 Asm[4096];
    __shared__ __align__(16) __bf16 Bsm[4096];
    const int z = blockIdx.z;
    const __bf16* Ab = A + (long long)z * sA;
    const __bf16* Bb = Bt + (long long)z * sB;
    const int bn = blockIdx.x, bm = blockIdx.y;
    const int tid = threadIdx.x;
    const int l = tid & 63, w = tid >> 6;
    const int wm = w >> 1, wn = w & 1;

    // staging: 512 chunks of 16B per tile; ch -> (kq=ch>>7, row=ch&127)
    const int ch0 = tid, ch1 = tid + 256;
    const int r0c = ch0 & 127, q0c = ch0 >> 7;
    const int r1c = ch1 & 127, q1c = ch1 >> 7;
    const __bf16* a0 = Ab + (long long)(bm * 128 + r0c) * K + q0c * 8;
    const __bf16* a1 = Ab + (long long)(bm * 128 + r1c) * K + q1c * 8;
    const __bf16* b0 = Bb + (long long)(bn * 128 + r0c) * K + q0c * 8;
    const __bf16* b1 = Bb + (long long)(bn * 128 + r1c) * K + q1c * 8;
    char* la0 = (char*)Asm + ch0 * 16;
    char* la1 = (char*)Asm + ch1 * 16;
    char* lb0 = (char*)Bsm + ch0 * 16;
    char* lb1 = (char*)Bsm + ch1 * 16;

    const int kq = l >> 4, r16 = l & 15;
    const __bf16* Afrag = Asm + kq * 1024 + (wm * 64 + r16) * 8;
    const __bf16* Bfrag = Bsm + kq * 1024 + (wn * 64 + r16) * 8;

    f32x4 acc[4][4] = {};

    for (int k0 = 0; k0 < K; k0 += 32) {
        gl_lds16(a0 + k0, la0);
        gl_lds16(a1 + k0, la1);
        gl_lds16(b0 + k0, lb0);
        gl_lds16(b1 + k0, lb1);
        __syncthreads();
        bf16x8 af[4], bfv[4];
#pragma unroll
        for (int i = 0; i < 4; ++i) {
            af[i]  = *(const bf16x8*)(Afrag + i * 128);  // +16 rows * 8
            bfv[i] = *(const bf16x8*)(Bfrag + i * 128);
        }
#pragma unroll
        for (int mi = 0; mi < 4; ++mi)
#pragma unroll
            for (int ni = 0; ni < 4; ++ni)
                acc[mi][ni] = __builtin_amdgcn_mfma_f32_16x16x32_bf16(
                    af[mi], bfv[ni], acc[mi][ni], 0, 0, 0);
        __syncthreads();
    }

    // epilogue: D row = quad*4+reg, col = lane&15 (guide-measured layout)
    const long long cbase = (long long)z * sC;
    const int quad = l >> 4;
#pragma unroll
    for (int mi = 0; mi < 4; ++mi) {
#pragma unroll
        for (int ni = 0; ni < 4; ++ni) {
            const int col = bn * 128 + wn * 64 + ni * 16 + r16;
            const float bv = HAS_BIAS ? bias[col] : 0.0f;
#pragma unroll
            for (int r = 0; r < 4; ++r) {
                const int row = bm * 128 + wm * 64 + mi * 16 + quad * 4 + r;
                const float v = acc[mi][ni][r] * scale + bv;
                if (OUT_F32)
                    ((float*)Cout)[cbase + (long long)row * N + col] = v;
                else
                    ((__bf16*)Cout)[cbase + (long long)row * N + col] = (__bf16)v;
            }
        }
    }
}

extern "C" void kernel_launch(void* const* d_in, const int* in_sizes, int n_in,
                              void* d_out, int out_size, void* d_ws, size_t ws_size,
                              hipStream_t stream) {
    const float* x  = (const float*)d_in[0];
    const float* wq = (const float*)d_in[1];
    const float* bq = (const float*)d_in[2];
    const float* wk = (const float*)d_in[3];
    const float* bk = (const float*)d_in[4];
    const float* wv = (const float*)d_in[5];
    const float* bv = (const float*)d_in[6];
    const float* wo = (const float*)d_in[7];
    const float* bo = (const float*)d_in[8];
    float* out = (float*)d_out;

    // ws layout (bf16 elems). E (67MB) reuses the Xb region (Xb dead after QKV).
    __bf16* ws  = (__bf16*)d_ws;
    __bf16* Xb  = ws;                   // 16,777,216 elems (phase 1)
    __bf16* E   = ws;                   // 33,554,432 elems (phase 2)
    __bf16* WT  = ws + 33554432;        // 4 x 1,048,576
    __bf16* Q   = ws + 37748736;        // 16,777,216
    __bf16* Kb  = ws + 54525952;        // 16,777,216
    __bf16* V   = ws + 71303168;        // 16,777,216 (reused as Ctx)
    __bf16* Vt  = ws + 88080384;        // 16,777,216   -> total 200 MiB
    __bf16* Ctx = V;

    k_convert<<<8192, 256, 0, stream>>>(x, Xb);
    k_transpose_w<<<dim3(16, 16), 256, 0, stream>>>(wq, WT);
    k_transpose_w<<<dim3(16, 16), 256, 0, stream>>>(wk, WT + 1048576);
    k_transpose_w<<<dim3(16, 16), 256, 0, stream>>>(wv, WT + 2097152);
    k_transpose_w<<<dim3(16, 16), 256, 0, stream>>>(wo, WT + 3145728);

    // QKV projections: [16384,1024] = Xb @ W^T + b
    gemm_bt<false, true><<<dim3(8, 128, 1), 256, 0, stream>>>(
        Xb, WT,           bq, Q,  16384, 1024, 1024, 1.0f, 0, 0, 0);
    gemm_bt<false, true><<<dim3(8, 128, 1), 256, 0, stream>>>(
        Xb, WT + 1048576, bk, Kb, 16384, 1024, 1024, 1.0f, 0, 0, 0);
    gemm_bt<false, true><<<dim3(8, 128, 1), 256, 0, stream>>>(
        Xb, WT + 2097152, bv, V,  16384, 1024, 1024, 1.0f, 0, 0, 0);

    k_transpose_v<<<dim3(16, 32, 8), 256, 0, stream>>>(V, Vt);

    // E[b] = Q[b] @ K[b]^T / sqrt(1024)
    gemm_bt<false, false><<<dim3(16, 16, 8), 256, 0, stream>>>(
        Q, Kb, nullptr, E, 2048, 2048, 1024, 0.03125f, 2097152, 2097152, 4194304);

    k_softmax<<<16384, 256, 0, stream>>>(E);

    // Ctx[b] = P[b] @ V[b]  (Vt is [h][s] = B^T layout)
    gemm_bt<false, false><<<dim3(8, 16, 8), 256, 0, stream>>>(
        E, Vt, nullptr, Ctx, 2048, 1024, 2048, 1.0f, 4194304, 2097152, 2097152);

    // out = Ctx @ Wo + bo (fp32 out)
    gemm_bt<true, true><<<dim3(8, 128, 1), 256, 0, stream>>>(
        Ctx, WT + 3145728, bo, out, 16384, 1024, 1024, 1.0f, 0, 0, 0);
}

// Round 3
// 736.879 us; speedup vs baseline: 1.1507x; 1.1507x over previous
//
#include <hip/hip_runtime.h>
#include <hip/hip_bf16.h>

// SpecAttn: out = softmax((x@Wq+bq)(x@Wk+bk)^T / 32) @ (x@Wv+bv) @ Wo + bo
// B=8, S=2048, H=1024. bf16 MFMA for all GEMMs, fp32 accumulate.
// R2: fused QKV GEMM (N=3072, epilogue writes Q, K, and V^T directly),
//     XCD-aware block swizzle for L2 A-tile reuse in all GEMMs.

typedef __attribute__((ext_vector_type(8))) __bf16 bf16x8;
typedef __attribute__((ext_vector_type(4))) __bf16 bf16x4;
typedef __attribute__((ext_vector_type(4))) float  f32x4;
typedef __attribute__((ext_vector_type(8))) float  f32x8;

__device__ __forceinline__ void gl_lds16(const void* g, void* l) {
    __builtin_amdgcn_global_load_lds(
        (__attribute__((address_space(1))) const void*)g,
        (__attribute__((address_space(3))) void*)l, 16, 0, 0);
}

// ---------------- fp32 -> bf16 convert (x) ----------------
__global__ __launch_bounds__(256) void k_convert(const float* __restrict__ in,
                                                 __bf16* __restrict__ out) {
    const int i = blockIdx.x * 256 + threadIdx.x;   // 8 elems/thread, exact fit
    f32x8 a = *((const f32x8*)in + i);
    bf16x8 o;
#pragma unroll
    for (int j = 0; j < 8; ++j) o[j] = (__bf16)a[j];
    *((bf16x8*)out + i) = o;
}

// ------------- fp32 W[k][n] -> bf16 Wt[n][k] (1024x1024) -------------
__global__ __launch_bounds__(256) void k_transpose_w(const float* __restrict__ W,
                                                     __bf16* __restrict__ Wt) {
    __shared__ float t[64][65];
    const int tid = threadIdx.x;
    const int c4 = (tid & 15) * 4, r0 = tid >> 4;
    const int bx = blockIdx.x * 64, by = blockIdx.y * 64;
#pragma unroll
    for (int p = 0; p < 4; ++p) {
        const int r = r0 + p * 16;
        f32x4 v = *(const f32x4*)(W + (long long)(by + r) * 1024 + bx + c4);
#pragma unroll
        for (int j = 0; j < 4; ++j) t[r][c4 + j] = v[j];
    }
    __syncthreads();
#pragma unroll
    for (int p = 0; p < 4; ++p) {
        const int r = r0 + p * 16;
        bf16x4 o;
#pragma unroll
        for (int j = 0; j < 4; ++j) o[j] = (__bf16)t[c4 + j][r];
        *(bf16x4*)(Wt + (long long)(bx + r) * 1024 + by + c4) = o;
    }
}

// ------------- concat biases into bcat[3072] fp32 -------------
__global__ __launch_bounds__(256) void k_bcat(const float* __restrict__ bq,
                                              const float* __restrict__ bk,
                                              const float* __restrict__ bv,
                                              float* __restrict__ bc) {
    const int i = blockIdx.x * 256 + threadIdx.x;  // grid 12 -> 3072
    const float* s = (i < 1024) ? bq : (i < 2048 ? bk : bv);
    bc[i] = s[i & 1023];
}

// ------------- row softmax over 2048 cols, in place, bf16 -------------
__global__ __launch_bounds__(256) void k_softmax(__bf16* __restrict__ E) {
    __bf16* p = E + (long long)blockIdx.x * 2048;
    const int tid = threadIdx.x, l = tid & 63, w = tid >> 6;
    bf16x8 vb = *((const bf16x8*)p + tid);
    float v[8];
#pragma unroll
    for (int i = 0; i < 8; ++i) v[i] = (float)vb[i];
    float m = v[0];
#pragma unroll
    for (int i = 1; i < 8; ++i) m = fmaxf(m, v[i]);
    for (int off = 32; off > 0; off >>= 1) m = fmaxf(m, __shfl_xor(m, off));
    __shared__ float redm[4], reds[4];
    if (l == 0) redm[w] = m;
    __syncthreads();
    m = fmaxf(fmaxf(redm[0], redm[1]), fmaxf(redm[2], redm[3]));
    float e[8], s = 0.f;
#pragma unroll
    for (int i = 0; i < 8; ++i) { e[i] = __expf(v[i] - m); s += e[i]; }
    for (int off = 32; off > 0; off >>= 1) s += __shfl_xor(s, off);
    if (l == 0) reds[w] = s;
    __syncthreads();
    s = reds[0] + reds[1] + reds[2] + reds[3];
    const float inv = 1.0f / s;
    bf16x8 o;
#pragma unroll
    for (int i = 0; i < 8; ++i) o[i] = (__bf16)(e[i] * inv);
    *((bf16x8*)p + tid) = o;
}

// ------------- GEMM: C[z] = A[z] @ Bt[z]^T * scale (+bias) -------------
// A:[M][lda] bf16; Bt:[N][ldb] bf16. Tiles 128x128, BK=32, 4 waves.
// 1D grid, XCD swizzle: lid%8 = XCD owns rows [xcd*rpx, xcd*rpx+rpx) of the
// global (z,bm) row-tile space; within XCD: groups of 8 bn-tiles outer,
// rows middle, bn inner -> A-tile used 8x back-to-back, 8 B-tiles stay in L2.
// MODE: 0 = bf16 C (generic), 1 = f32 C (generic), 2 = QKV split epilogue
//       (cols 0-1023 -> Q[b][s][h], 1024-2047 -> K[b][s][h],
//        2048-3071 -> Vt[b][h][s]; Q/K/Vt contiguous from Cout).
template <int MODE, bool HAS_BIAS>
__global__ __launch_bounds__(256) void gemm_bt(
    const __bf16* __restrict__ A, const __bf16* __restrict__ Bt,
    const float* __restrict__ bias, void* __restrict__ Cout,
    int K, int lda, int ldb, int ldc, int gy, int rpx,
    float scale, long long sA, long long sB, long long sC) {
    __shared__ __align__(16) __bf16 Asm[4096];
    __shared__ __align__(16) __bf16 Bsm[4096];

    // swizzled block mapping
    const int lid = blockIdx.x;
    const int xcd = lid & 7;
    const int j = lid >> 3;
    const int grpsz = rpx * 8;
    const int g = j / grpsz;
    const int rem = j - g * grpsz;
    const int r_local = rem >> 3;
    const int bn = g * 8 + (rem & 7);
    const int row_t = xcd * rpx + r_local;
    const int z = row_t / gy;
    const int bm = row_t - z * gy;

    const __bf16* Ab = A + (long long)z * sA;
    const __bf16* Bb = Bt + (long long)z * sB;
    const int tid = threadIdx.x;
    const int l = tid & 63, w = tid >> 6;
    const int wm = w >> 1, wn = w & 1;

    // staging: 512 chunks of 16B per tile; ch -> (kq=ch>>7, row=ch&127)
    const int ch0 = tid, ch1 = tid + 256;
    const int r0c = ch0 & 127, q0c = ch0 >> 7;
    const int r1c = ch1 & 127, q1c = ch1 >> 7;
    const __bf16* a0 = Ab + (long long)(bm * 128 + r0c) * lda + q0c * 8;
    const __bf16* a1 = Ab + (long long)(bm * 128 + r1c) * lda + q1c * 8;
    const __bf16* b0 = Bb + (long long)(bn * 128 + r0c) * ldb + q0c * 8;
    const __bf16* b1 = Bb + (long long)(bn * 128 + r1c) * ldb + q1c * 8;
    char* la0 = (char*)Asm + ch0 * 16;
    char* la1 = (char*)Asm + ch1 * 16;
    char* lb0 = (char*)Bsm + ch0 * 16;
    char* lb1 = (char*)Bsm + ch1 * 16;

    const int kq = l >> 4, r16 = l & 15;
    const __bf16* Afrag = Asm + kq * 1024 + (wm * 64 + r16) * 8;
    const __bf16* Bfrag = Bsm + kq * 1024 + (wn * 64 + r16) * 8;

    f32x4 acc[4][4] = {};

    for (int k0 = 0; k0 < K; k0 += 32) {
        gl_lds16(a0 + k0, la0);
        gl_lds16(a1 + k0, la1);
        gl_lds16(b0 + k0, lb0);
        gl_lds16(b1 + k0, lb1);
        __syncthreads();
        bf16x8 af[4], bfv[4];
#pragma unroll
        for (int i = 0; i < 4; ++i) {
            af[i]  = *(const bf16x8*)(Afrag + i * 128);
            bfv[i] = *(const bf16x8*)(Bfrag + i * 128);
        }
#pragma unroll
        for (int mi = 0; mi < 4; ++mi)
#pragma unroll
            for (int ni = 0; ni < 4; ++ni)
                acc[mi][ni] = __builtin_amdgcn_mfma_f32_16x16x32_bf16(
                    af[mi], bfv[ni], acc[mi][ni], 0, 0, 0);
        __syncthreads();
    }

    // epilogue: D row = quad*4+reg, col = lane&15
    const int quad = l >> 4;
    if (MODE == 2) {
        __bf16* Qb = (__bf16*)Cout;
        const int part = bn >> 3;  // 0=Q 1=K 2=V
#pragma unroll
        for (int mi = 0; mi < 4; ++mi) {
            const int srow0 = bm * 128 + wm * 64 + mi * 16 + quad * 4;
            const int b = srow0 >> 11;
            const int s0 = srow0 & 2047;
#pragma unroll
            for (int ni = 0; ni < 4; ++ni) {
                const int col = bn * 128 + wn * 64 + ni * 16 + r16;
                const float bb = HAS_BIAS ? bias[col] : 0.0f;
                const int c1 = col - part * 1024;
                if (part == 2) {
                    bf16x4 o;
#pragma unroll
                    for (int r = 0; r < 4; ++r) o[r] = (__bf16)(acc[mi][ni][r] + bb);
                    *(bf16x4*)(Qb + 33554432 + (long long)b * 2097152 +
                               (long long)c1 * 2048 + s0) = o;
                } else {
                    __bf16* dst = Qb + (long long)part * 16777216 +
                                  (long long)b * 2097152 + (long long)s0 * 1024 + c1;
#pragma unroll
                    for (int r = 0; r < 4; ++r) dst[r * 1024] = (__bf16)(acc[mi][ni][r] + bb);
                }
            }
        }
    } else {
        const long long cbase = (long long)z * sC;
#pragma unroll
        for (int mi = 0; mi < 4; ++mi) {
#pragma unroll
            for (int ni = 0; ni < 4; ++ni) {
                const int col = bn * 128 + wn * 64 + ni * 16 + r16;
                const float bb = HAS_BIAS ? bias[col] : 0.0f;
#pragma unroll
                for (int r = 0; r < 4; ++r) {
                    const int row = bm * 128 + wm * 64 + mi * 16 + quad * 4 + r;
                    const float v = acc[mi][ni][r] * scale + bb;
                    if (MODE == 1)
                        ((float*)Cout)[cbase + (long long)row * ldc + col] = v;
                    else
                        ((__bf16*)Cout)[cbase + (long long)row * ldc + col] = (__bf16)v;
                }
            }
        }
    }
}

extern "C" void kernel_launch(void* const* d_in, const int* in_sizes, int n_in,
                              void* d_out, int out_size, void* d_ws, size_t ws_size,
                              hipStream_t stream) {
    const float* x  = (const float*)d_in[0];
    const float* wq = (const float*)d_in[1];
    const float* bq = (const float*)d_in[2];
    const float* wk = (const float*)d_in[3];
    const float* bk = (const float*)d_in[4];
    const float* wv = (const float*)d_in[5];
    const float* bv = (const float*)d_in[6];
    const float* wo = (const float*)d_in[7];
    const float* bo = (const float*)d_in[8];
    float* out = (float*)d_out;

    // ws layout (bf16 elems), ~200 MiB total.
    // Q, Kb, Vt must be contiguous in that order (MODE 2 epilogue).
    __bf16* ws  = (__bf16*)d_ws;
    __bf16* Xb  = ws;                   // 16,777,216 (phase 1; dead after QKV)
    __bf16* E   = ws;                   // 33,554,432 (phase 2, reuses Xb)
    __bf16* Q   = ws + 33554432;        // 16,777,216
    __bf16* Kb  = ws + 50331648;        // 16,777,216
    __bf16* Vt  = ws + 67108864;        // 16,777,216
    __bf16* Ctx = ws + 83886080;        // 16,777,216
    __bf16* WT  = ws + 100663296;       // 4,194,304
    float*  bc  = (float*)(ws + 104857600);  // 3072 fp32

    k_convert<<<8192, 256, 0, stream>>>(x, Xb);
    k_transpose_w<<<dim3(16, 16), 256, 0, stream>>>(wq, WT);
    k_transpose_w<<<dim3(16, 16), 256, 0, stream>>>(wk, WT + 1048576);
    k_transpose_w<<<dim3(16, 16), 256, 0, stream>>>(wv, WT + 2097152);
    k_transpose_w<<<dim3(16, 16), 256, 0, stream>>>(wo, WT + 3145728);
    k_bcat<<<12, 256, 0, stream>>>(bq, bk, bv, bc);

    // Fused QKV: [16384,3072] = Xb @ WT^T + bcat; writes Q, K, V^T
    // gx=24, gy=128, Z=1, rpx=128/8=16
    gemm_bt<2, true><<<3072, 256, 0, stream>>>(
        Xb, WT, bc, Q, 1024, 1024, 1024, 0, 128, 16, 1.0f, 0, 0, 0);

    // E[b] = Q[b] @ K[b]^T / 32   gx=16, gy=16, Z=8, rpx=16 (one batch/XCD)
    gemm_bt<0, false><<<2048, 256, 0, stream>>>(
        Q, Kb, nullptr, E, 1024, 1024, 1024, 2048, 16, 16,
        0.03125f, 2097152, 2097152, 4194304);

    k_softmax<<<16384, 256, 0, stream>>>(E);

    // Ctx[b] = P[b] @ Vt[b]^T    gx=8, gy=16, Z=8, rpx=16
    gemm_bt<0, false><<<1024, 256, 0, stream>>>(
        E, Vt, nullptr, Ctx, 2048, 2048, 2048, 1024, 16, 16,
        1.0f, 4194304, 2097152, 2097152);

    // out = Ctx @ Wo^T + bo (fp32)  gx=8, gy=128, Z=1, rpx=16
    gemm_bt<1, true><<<1024, 256, 0, stream>>>(
        Ctx, WT + 3145728, bo, out, 1024, 1024, 1024, 1024, 128, 16,
        1.0f, 0, 0, 0);
}

// Round 4
// 702.344 us; speedup vs baseline: 1.2073x; 1.0492x over previous
//
#include <hip/hip_runtime.h>
#include <hip/hip_bf16.h>

// SpecAttn: out = softmax((x@Wq+bq)(x@Wk+bk)^T / 32) @ (x@Wv+bv) @ Wo + bo
// B=8, S=2048, H=1024. bf16 MFMA everywhere, fp32 accumulate.
// R3: 256x128 tile / 8 waves / BK=64 to amortize per-block fixed costs
//     (K=1024 means only 16 iters; prologue+epilogue dominated at 128x128).

typedef __attribute__((ext_vector_type(8))) __bf16 bf16x8;
typedef __attribute__((ext_vector_type(4))) __bf16 bf16x4;
typedef __attribute__((ext_vector_type(4))) float  f32x4;
typedef __attribute__((ext_vector_type(8))) float  f32x8;

__device__ __forceinline__ void gl_lds16(const void* g, void* l) {
    __builtin_amdgcn_global_load_lds(
        (__attribute__((address_space(1))) const void*)g,
        (__attribute__((address_space(3))) void*)l, 16, 0, 0);
}

// ---------------- fp32 -> bf16 convert (x) ----------------
__global__ __launch_bounds__(256) void k_convert(const float* __restrict__ in,
                                                 __bf16* __restrict__ out) {
    const int i = blockIdx.x * 256 + threadIdx.x;   // 8 elems/thread, exact fit
    f32x8 a = *((const f32x8*)in + i);
    bf16x8 o;
#pragma unroll
    for (int j = 0; j < 8; ++j) o[j] = (__bf16)a[j];
    *((bf16x8*)out + i) = o;
}

// --- fp32 W[k][n] -> bf16 Wt[n][k] (1024x1024), z selects weight ---
__global__ __launch_bounds__(256) void k_transpose_w(
    const float* __restrict__ w0, const float* __restrict__ w1,
    const float* __restrict__ w2, const float* __restrict__ w3,
    __bf16* __restrict__ Wt) {
    const int z = blockIdx.z;
    const float* W = (z == 0) ? w0 : (z == 1) ? w1 : (z == 2) ? w2 : w3;
    __bf16* Wo = Wt + (long long)z * 1048576;
    __shared__ float t[64][65];
    const int tid = threadIdx.x;
    const int c4 = (tid & 15) * 4, r0 = tid >> 4;
    const int bx = blockIdx.x * 64, by = blockIdx.y * 64;
#pragma unroll
    for (int p = 0; p < 4; ++p) {
        const int r = r0 + p * 16;
        f32x4 v = *(const f32x4*)(W + (long long)(by + r) * 1024 + bx + c4);
#pragma unroll
        for (int j = 0; j < 4; ++j) t[r][c4 + j] = v[j];
    }
    __syncthreads();
#pragma unroll
    for (int p = 0; p < 4; ++p) {
        const int r = r0 + p * 16;
        bf16x4 o;
#pragma unroll
        for (int j = 0; j < 4; ++j) o[j] = (__bf16)t[c4 + j][r];
        *(bf16x4*)(Wo + (long long)(bx + r) * 1024 + by + c4) = o;
    }
}

// ------------- concat biases into bcat[3072] fp32 -------------
__global__ __launch_bounds__(256) void k_bcat(const float* __restrict__ bq,
                                              const float* __restrict__ bk,
                                              const float* __restrict__ bv,
                                              float* __restrict__ bc) {
    const int i = blockIdx.x * 256 + threadIdx.x;  // grid 12 -> 3072
    const float* s = (i < 1024) ? bq : (i < 2048 ? bk : bv);
    bc[i] = s[i & 1023];
}

// ------------- row softmax over 2048 cols, in place, bf16 -------------
__global__ __launch_bounds__(256) void k_softmax(__bf16* __restrict__ E) {
    __bf16* p = E + (long long)blockIdx.x * 2048;
    const int tid = threadIdx.x, l = tid & 63, w = tid >> 6;
    bf16x8 vb = *((const bf16x8*)p + tid);
    float v[8];
#pragma unroll
    for (int i = 0; i < 8; ++i) v[i] = (float)vb[i];
    float m = v[0];
#pragma unroll
    for (int i = 1; i < 8; ++i) m = fmaxf(m, v[i]);
    for (int off = 32; off > 0; off >>= 1) m = fmaxf(m, __shfl_xor(m, off));
    __shared__ float redm[4], reds[4];
    if (l == 0) redm[w] = m;
    __syncthreads();
    m = fmaxf(fmaxf(redm[0], redm[1]), fmaxf(redm[2], redm[3]));
    float e[8], s = 0.f;
#pragma unroll
    for (int i = 0; i < 8; ++i) { e[i] = __expf(v[i] - m); s += e[i]; }
    for (int off = 32; off > 0; off >>= 1) s += __shfl_xor(s, off);
    if (l == 0) reds[w] = s;
    __syncthreads();
    s = reds[0] + reds[1] + reds[2] + reds[3];
    const float inv = 1.0f / s;
    bf16x8 o;
#pragma unroll
    for (int i = 0; i < 8; ++i) o[i] = (__bf16)(e[i] * inv);
    *((bf16x8*)p + tid) = o;
}

// ------------- GEMM: C[z] = A[z] @ Bt[z]^T * scale (+bias) -------------
// Tiles 256x128, BK=64, 512 threads / 8 waves (wave tile 64x64, 4x4 16x16x32).
// LDS: A [kh 8][row 256][8] 32KB, B [kh 8][row 128][8] 16KB.
// 1D grid XCD swizzle (lid%8 = XCD), bn inner in groups of 8.
// MODE: 0 = bf16 C, 1 = f32 C, 2 = QKV split epilogue
//       (cols 0-1023 -> Q[b][s][h], 1024-2047 -> K[b][s][h],
//        2048-3071 -> Vt[b][h][s]; Q/K/Vt contiguous from Cout).
template <int MODE, bool HAS_BIAS>
__global__ __launch_bounds__(512, 4) void gemm_bt(
    const __bf16* __restrict__ A, const __bf16* __restrict__ Bt,
    const float* __restrict__ bias, void* __restrict__ Cout,
    int K, int lda, int ldb, int ldc, int gy, int rpx,
    float scale, long long sA, long long sB, long long sC) {
    __shared__ __align__(16) __bf16 Asm[16384];  // 32 KB
    __shared__ __align__(16) __bf16 Bsm[8192];   // 16 KB

    // swizzled block mapping
    const int lid = blockIdx.x;
    const int xcd = lid & 7;
    const int j = lid >> 3;
    const int grpsz = rpx * 8;
    const int g = j / grpsz;
    const int rem = j - g * grpsz;
    const int r_local = rem >> 3;
    const int bn = g * 8 + (rem & 7);
    const int row_t = xcd * rpx + r_local;
    const int z = row_t / gy;
    const int bm = row_t - z * gy;

    const __bf16* Ab = A + (long long)z * sA;
    const __bf16* Bb = Bt + (long long)z * sB;
    const int tid = threadIdx.x;
    const int l = tid & 63, w = tid >> 6;
    const int wm = w >> 1, wn = w & 1;   // wm in [0,4), wn in [0,2)

    // staging: A 2048 chunks (4/thread), B 1024 chunks (2/thread), 16B each
    const __bf16* gA[4];
    char* lA[4];
#pragma unroll
    for (int i = 0; i < 4; ++i) {
        const int ch = tid + 512 * i;
        const int kh = ch >> 8, row = ch & 255;
        gA[i] = Ab + (long long)(bm * 256 + row) * lda + kh * 8;
        lA[i] = (char*)Asm + ch * 16;
    }
    const __bf16* gB[2];
    char* lB[2];
#pragma unroll
    for (int i = 0; i < 2; ++i) {
        const int ch = tid + 512 * i;
        const int kh = ch >> 7, row = ch & 127;
        gB[i] = Bb + (long long)(bn * 128 + row) * ldb + kh * 8;
        lB[i] = (char*)Bsm + ch * 16;
    }

    const int kq = l >> 4, r16 = l & 15;

    f32x4 acc[4][4] = {};

    for (int k0 = 0; k0 < K; k0 += 64) {
#pragma unroll
        for (int i = 0; i < 4; ++i) gl_lds16(gA[i] + k0, lA[i]);
#pragma unroll
        for (int i = 0; i < 2; ++i) gl_lds16(gB[i] + k0, lB[i]);
        __syncthreads();
#pragma unroll
        for (int ks = 0; ks < 2; ++ks) {
            const __bf16* Afrag = Asm + ((ks * 4 + kq) * 256 + wm * 64 + r16) * 8;
            const __bf16* Bfrag = Bsm + ((ks * 4 + kq) * 128 + wn * 64 + r16) * 8;
            bf16x8 af[4], bfv[4];
#pragma unroll
            for (int i = 0; i < 4; ++i) {
                af[i]  = *(const bf16x8*)(Afrag + i * 128);  // +16 rows * 8
                bfv[i] = *(const bf16x8*)(Bfrag + i * 128);
            }
#pragma unroll
            for (int mi = 0; mi < 4; ++mi)
#pragma unroll
                for (int ni = 0; ni < 4; ++ni)
                    acc[mi][ni] = __builtin_amdgcn_mfma_f32_16x16x32_bf16(
                        af[mi], bfv[ni], acc[mi][ni], 0, 0, 0);
        }
        __syncthreads();
    }

    // epilogue: D row = quad*4+reg, col = lane&15
    const int quad = l >> 4;
    if (MODE == 2) {
        __bf16* Qb = (__bf16*)Cout;
        const int part = bn >> 3;  // 0=Q 1=K 2=V
#pragma unroll
        for (int mi = 0; mi < 4; ++mi) {
            const int srow0 = bm * 256 + wm * 64 + mi * 16 + quad * 4;
            const int b = srow0 >> 11;
            const int s0 = srow0 & 2047;
#pragma unroll
            for (int ni = 0; ni < 4; ++ni) {
                const int col = bn * 128 + wn * 64 + ni * 16 + r16;
                const float bb = HAS_BIAS ? bias[col] : 0.0f;
                const int c1 = col - part * 1024;
                if (part == 2) {
                    bf16x4 o;
#pragma unroll
                    for (int r = 0; r < 4; ++r) o[r] = (__bf16)(acc[mi][ni][r] + bb);
                    *(bf16x4*)(Qb + 33554432 + (long long)b * 2097152 +
                               (long long)c1 * 2048 + s0) = o;
                } else {
                    __bf16* dst = Qb + (long long)part * 16777216 +
                                  (long long)b * 2097152 + (long long)s0 * 1024 + c1;
#pragma unroll
                    for (int r = 0; r < 4; ++r) dst[r * 1024] = (__bf16)(acc[mi][ni][r] + bb);
                }
            }
        }
    } else {
        const long long cbase = (long long)z * sC;
#pragma unroll
        for (int mi = 0; mi < 4; ++mi) {
#pragma unroll
            for (int ni = 0; ni < 4; ++ni) {
                const int col = bn * 128 + wn * 64 + ni * 16 + r16;
                const float bb = HAS_BIAS ? bias[col] : 0.0f;
#pragma unroll
                for (int r = 0; r < 4; ++r) {
                    const int row = bm * 256 + wm * 64 + mi * 16 + quad * 4 + r;
                    const float v = acc[mi][ni][r] * scale + bb;
                    if (MODE == 1)
                        ((float*)Cout)[cbase + (long long)row * ldc + col] = v;
                    else
                        ((__bf16*)Cout)[cbase + (long long)row * ldc + col] = (__bf16)v;
                }
            }
        }
    }
}

extern "C" void kernel_launch(void* const* d_in, const int* in_sizes, int n_in,
                              void* d_out, int out_size, void* d_ws, size_t ws_size,
                              hipStream_t stream) {
    const float* x  = (const float*)d_in[0];
    const float* wq = (const float*)d_in[1];
    const float* bq = (const float*)d_in[2];
    const float* wk = (const float*)d_in[3];
    const float* bk = (const float*)d_in[4];
    const float* wv = (const float*)d_in[5];
    const float* bv = (const float*)d_in[6];
    const float* wo = (const float*)d_in[7];
    const float* bo = (const float*)d_in[8];
    float* out = (float*)d_out;

    // ws layout (bf16 elems), ~200 MiB total.
    // Q, Kb, Vt must be contiguous in that order (MODE 2 epilogue).
    __bf16* ws  = (__bf16*)d_ws;
    __bf16* Xb  = ws;                   // 16,777,216 (phase 1; dead after QKV)
    __bf16* E   = ws;                   // 33,554,432 (phase 2, reuses Xb)
    __bf16* Q   = ws + 33554432;        // 16,777,216
    __bf16* Kb  = ws + 50331648;        // 16,777,216
    __bf16* Vt  = ws + 67108864;        // 16,777,216
    __bf16* Ctx = ws + 83886080;        // 16,777,216
    __bf16* WT  = ws + 100663296;       // 4,194,304
    float*  bc  = (float*)(ws + 104857600);  // 3072 fp32

    k_convert<<<8192, 256, 0, stream>>>(x, Xb);
    k_transpose_w<<<dim3(16, 16, 4), 256, 0, stream>>>(wq, wk, wv, wo, WT);
    k_bcat<<<12, 256, 0, stream>>>(bq, bk, bv, bc);

    // Fused QKV: [16384,3072] = Xb @ WT^T + bcat; writes Q, K, V^T
    // row-tiles 64, bn-tiles 24 -> 1536 blocks; gy=64, rpx=8
    gemm_bt<2, true><<<1536, 512, 0, stream>>>(
        Xb, WT, bc, Q, 1024, 1024, 1024, 0, 64, 8, 1.0f, 0, 0, 0);

    // E[b] = Q[b] @ K[b]^T / 32   row-tiles 8/z * 8 = 64, bn 16 -> 1024 blocks
    gemm_bt<0, false><<<1024, 512, 0, stream>>>(
        Q, Kb, nullptr, E, 1024, 1024, 1024, 2048, 8, 8,
        0.03125f, 2097152, 2097152, 4194304);

    k_softmax<<<16384, 256, 0, stream>>>(E);

    // Ctx[b] = P[b] @ Vt[b]^T    row-tiles 64, bn 8 -> 512 blocks
    gemm_bt<0, false><<<512, 512, 0, stream>>>(
        E, Vt, nullptr, Ctx, 2048, 2048, 2048, 1024, 8, 8,
        1.0f, 4194304, 2097152, 2097152);

    // out = Ctx @ Wo^T + bo (fp32)  row-tiles 64, bn 8 -> 512 blocks
    gemm_bt<1, true><<<512, 512, 0, stream>>>(
        Ctx, WT + 3145728, bo, out, 1024, 1024, 1024, 1024, 64, 8,
        1.0f, 0, 0, 0);
}

// Round 5
// 699.399 us; speedup vs baseline: 1.2124x; 1.0042x over previous
//
#include <hip/hip_runtime.h>
#include <hip/hip_bf16.h>

// SpecAttn: out = softmax((x@Wq+bq)(x@Wk+bk)^T / 32) @ (x@Wv+bv) @ Wo + bo
// B=8, S=2048, H=1024. bf16 MFMA everywhere, fp32 accumulate.
// R5: software-pipelined K-loop. Double-buffered LDS (4 distinct static
//     __shared__ arrays so AA keeps the compiler from inserting vmcnt(0)
//     between prefetch-issue and the other buffer's ds_reads), ONE barrier
//     per BK=32 stage, prefetch depth 1: each global_load_lds batch has a
//     full compute phase to land. 128x128 tile, 4 waves, 32KB LDS,
//     launch_bounds(256,4) -> 4 blocks/CU for cross-block TLP.

typedef __attribute__((ext_vector_type(8))) __bf16 bf16x8;
typedef __attribute__((ext_vector_type(4))) __bf16 bf16x4;
typedef __attribute__((ext_vector_type(4))) float  f32x4;
typedef __attribute__((ext_vector_type(8))) float  f32x8;

__device__ __forceinline__ void gl_lds16(const void* g, void* l) {
    __builtin_amdgcn_global_load_lds(
        (__attribute__((address_space(1))) const void*)g,
        (__attribute__((address_space(3))) void*)l, 16, 0, 0);
}

// ---------------- fp32 -> bf16 convert (x) ----------------
__global__ __launch_bounds__(256) void k_convert(const float* __restrict__ in,
                                                 __bf16* __restrict__ out) {
    const int i = blockIdx.x * 256 + threadIdx.x;   // 8 elems/thread, exact fit
    f32x8 a = *((const f32x8*)in + i);
    bf16x8 o;
#pragma unroll
    for (int j = 0; j < 8; ++j) o[j] = (__bf16)a[j];
    *((bf16x8*)out + i) = o;
}

// --- fp32 W[k][n] -> bf16 Wt[n][k] (1024x1024), z selects weight ---
__global__ __launch_bounds__(256) void k_transpose_w(
    const float* __restrict__ w0, const float* __restrict__ w1,
    const float* __restrict__ w2, const float* __restrict__ w3,
    __bf16* __restrict__ Wt) {
    const int z = blockIdx.z;
    const float* W = (z == 0) ? w0 : (z == 1) ? w1 : (z == 2) ? w2 : w3;
    __bf16* Wo = Wt + (long long)z * 1048576;
    __shared__ float t[64][65];
    const int tid = threadIdx.x;
    const int c4 = (tid & 15) * 4, r0 = tid >> 4;
    const int bx = blockIdx.x * 64, by = blockIdx.y * 64;
#pragma unroll
    for (int p = 0; p < 4; ++p) {
        const int r = r0 + p * 16;
        f32x4 v = *(const f32x4*)(W + (long long)(by + r) * 1024 + bx + c4);
#pragma unroll
        for (int j = 0; j < 4; ++j) t[r][c4 + j] = v[j];
    }
    __syncthreads();
#pragma unroll
    for (int p = 0; p < 4; ++p) {
        const int r = r0 + p * 16;
        bf16x4 o;
#pragma unroll
        for (int j = 0; j < 4; ++j) o[j] = (__bf16)t[c4 + j][r];
        *(bf16x4*)(Wo + (long long)(bx + r) * 1024 + by + c4) = o;
    }
}

// ------------- concat biases into bcat[3072] fp32 -------------
__global__ __launch_bounds__(256) void k_bcat(const float* __restrict__ bq,
                                              const float* __restrict__ bk,
                                              const float* __restrict__ bv,
                                              float* __restrict__ bc) {
    const int i = blockIdx.x * 256 + threadIdx.x;  // grid 12 -> 3072
    const float* s = (i < 1024) ? bq : (i < 2048 ? bk : bv);
    bc[i] = s[i & 1023];
}

// ------------- row softmax over 2048 cols, in place, bf16 -------------
__global__ __launch_bounds__(256) void k_softmax(__bf16* __restrict__ E) {
    __bf16* p = E + (long long)blockIdx.x * 2048;
    const int tid = threadIdx.x, l = tid & 63, w = tid >> 6;
    bf16x8 vb = *((const bf16x8*)p + tid);
    float v[8];
#pragma unroll
    for (int i = 0; i < 8; ++i) v[i] = (float)vb[i];
    float m = v[0];
#pragma unroll
    for (int i = 1; i < 8; ++i) m = fmaxf(m, v[i]);
    for (int off = 32; off > 0; off >>= 1) m = fmaxf(m, __shfl_xor(m, off));
    __shared__ float redm[4], reds[4];
    if (l == 0) redm[w] = m;
    __syncthreads();
    m = fmaxf(fmaxf(redm[0], redm[1]), fmaxf(redm[2], redm[3]));
    float e[8], s = 0.f;
#pragma unroll
    for (int i = 0; i < 8; ++i) { e[i] = __expf(v[i] - m); s += e[i]; }
    for (int off = 32; off > 0; off >>= 1) s += __shfl_xor(s, off);
    if (l == 0) reds[w] = s;
    __syncthreads();
    s = reds[0] + reds[1] + reds[2] + reds[3];
    const float inv = 1.0f / s;
    bf16x8 o;
#pragma unroll
    for (int i = 0; i < 8; ++i) o[i] = (__bf16)(e[i] * inv);
    *((bf16x8*)p + tid) = o;
}

// ------------- GEMM: C[z] = A[z] @ Bt[z]^T * scale (+bias) -------------
// 128x128 tile, BK=32, 4 waves (wave tile 64x64 = 4x4 of 16x16x32).
// Double-buffered LDS (A0/B0/A1/B1 distinct arrays), 1 barrier per stage.
// 1D grid XCD swizzle (lid%8 = XCD), bn inner in groups of 8.
// MODE: 0 = bf16 C, 1 = f32 C, 2 = QKV split epilogue
//       (cols 0-1023 -> Q[b][s][h], 1024-2047 -> K[b][s][h],
//        2048-3071 -> Vt[b][h][s]; Q/K/Vt contiguous from Cout).
template <int MODE, bool HAS_BIAS>
__global__ __launch_bounds__(256, 4) void gemm_bt(
    const __bf16* __restrict__ A, const __bf16* __restrict__ Bt,
    const float* __restrict__ bias, void* __restrict__ Cout,
    int K, int lda, int ldb, int ldc, int gy, int rpx,
    float scale, long long sA, long long sB, long long sC) {
    __shared__ __align__(16) __bf16 A0[4096];
    __shared__ __align__(16) __bf16 B0[4096];
    __shared__ __align__(16) __bf16 A1[4096];
    __shared__ __align__(16) __bf16 B1[4096];

    // swizzled block mapping
    const int lid = blockIdx.x;
    const int xcd = lid & 7;
    const int j = lid >> 3;
    const int grpsz = rpx * 8;
    const int g = j / grpsz;
    const int rem = j - g * grpsz;
    const int r_local = rem >> 3;
    const int bn = g * 8 + (rem & 7);
    const int row_t = xcd * rpx + r_local;
    const int z = row_t / gy;
    const int bm = row_t - z * gy;

    const __bf16* Ab = A + (long long)z * sA;
    const __bf16* Bb = Bt + (long long)z * sB;
    const int tid = threadIdx.x;
    const int l = tid & 63, w = tid >> 6;
    const int wm = w >> 1, wn = w & 1;

    // staging: 512 chunks of 16B per tile; ch -> (kq=ch>>7, row=ch&127)
    const int ch0 = tid, ch1 = tid + 256;
    const int r0c = ch0 & 127, q0c = ch0 >> 7;
    const int r1c = ch1 & 127, q1c = ch1 >> 7;
    const __bf16* a0 = Ab + (long long)(bm * 128 + r0c) * lda + q0c * 8;
    const __bf16* a1 = Ab + (long long)(bm * 128 + r1c) * lda + q1c * 8;
    const __bf16* b0 = Bb + (long long)(bn * 128 + r0c) * ldb + q0c * 8;
    const __bf16* b1 = Bb + (long long)(bn * 128 + r1c) * ldb + q1c * 8;
    const int lo0 = ch0 * 16, lo1 = ch1 * 16;

    const int kq = l >> 4, r16 = l & 15;
    const int afo = kq * 1024 + (wm * 64 + r16) * 8;
    const int bfo = kq * 1024 + (wn * 64 + r16) * 8;

    f32x4 acc[4][4] = {};

#define STAGE(As, Bs, k0)                      \
    do {                                       \
        gl_lds16(a0 + (k0), (char*)(As) + lo0); \
        gl_lds16(a1 + (k0), (char*)(As) + lo1); \
        gl_lds16(b0 + (k0), (char*)(Bs) + lo0); \
        gl_lds16(b1 + (k0), (char*)(Bs) + lo1); \
    } while (0)

#define COMPUTE(As, Bs)                                                   \
    do {                                                                  \
        const __bf16* Af = (As) + afo;                                    \
        const __bf16* Bf = (Bs) + bfo;                                    \
        bf16x8 af[4], bfv[4];                                             \
        _Pragma("unroll") for (int i = 0; i < 4; ++i) {                   \
            af[i]  = *(const bf16x8*)(Af + i * 128);                      \
            bfv[i] = *(const bf16x8*)(Bf + i * 128);                      \
        }                                                                 \
        _Pragma("unroll") for (int mi = 0; mi < 4; ++mi)                  \
            _Pragma("unroll") for (int ni = 0; ni < 4; ++ni)              \
                acc[mi][ni] = __builtin_amdgcn_mfma_f32_16x16x32_bf16(    \
                    af[mi], bfv[ni], acc[mi][ni], 0, 0, 0);               \
    } while (0)

    STAGE(A0, B0, 0);
    for (int k0 = 0; k0 < K; k0 += 64) {
        __syncthreads();                       // drains batch k0 (vmcnt(0))
        if (k0 + 32 < K) STAGE(A1, B1, k0 + 32);
        COMPUTE(A0, B0);
        __syncthreads();                       // drains batch k0+32
        if (k0 + 64 < K) STAGE(A0, B0, k0 + 64);
        COMPUTE(A1, B1);
    }
#undef STAGE
#undef COMPUTE

    // epilogue: D row = quad*4+reg, col = lane&15
    const int quad = l >> 4;
    if (MODE == 2) {
        __bf16* Qb = (__bf16*)Cout;
        const int part = bn >> 3;  // 0=Q 1=K 2=V
#pragma unroll
        for (int mi = 0; mi < 4; ++mi) {
            const int srow0 = bm * 128 + wm * 64 + mi * 16 + quad * 4;
            const int b = srow0 >> 11;
            const int s0 = srow0 & 2047;
#pragma unroll
            for (int ni = 0; ni < 4; ++ni) {
                const int col = bn * 128 + wn * 64 + ni * 16 + r16;
                const float bb = HAS_BIAS ? bias[col] : 0.0f;
                const int c1 = col - part * 1024;
                if (part == 2) {
                    bf16x4 o;
#pragma unroll
                    for (int r = 0; r < 4; ++r) o[r] = (__bf16)(acc[mi][ni][r] + bb);
                    *(bf16x4*)(Qb + 33554432 + (long long)b * 2097152 +
                               (long long)c1 * 2048 + s0) = o;
                } else {
                    __bf16* dst = Qb + (long long)part * 16777216 +
                                  (long long)b * 2097152 + (long long)s0 * 1024 + c1;
#pragma unroll
                    for (int r = 0; r < 4; ++r) dst[r * 1024] = (__bf16)(acc[mi][ni][r] + bb);
                }
            }
        }
    } else {
        const long long cbase = (long long)z * sC;
#pragma unroll
        for (int mi = 0; mi < 4; ++mi) {
#pragma unroll
            for (int ni = 0; ni < 4; ++ni) {
                const int col = bn * 128 + wn * 64 + ni * 16 + r16;
                const float bb = HAS_BIAS ? bias[col] : 0.0f;
#pragma unroll
                for (int r = 0; r < 4; ++r) {
                    const int row = bm * 128 + wm * 64 + mi * 16 + quad * 4 + r;
                    const float v = acc[mi][ni][r] * scale + bb;
                    if (MODE == 1)
                        ((float*)Cout)[cbase + (long long)row * ldc + col] = v;
                    else
                        ((__bf16*)Cout)[cbase + (long long)row * ldc + col] = (__bf16)v;
                }
            }
        }
    }
}

extern "C" void kernel_launch(void* const* d_in, const int* in_sizes, int n_in,
                              void* d_out, int out_size, void* d_ws, size_t ws_size,
                              hipStream_t stream) {
    const float* x  = (const float*)d_in[0];
    const float* wq = (const float*)d_in[1];
    const float* bq = (const float*)d_in[2];
    const float* wk = (const float*)d_in[3];
    const float* bk = (const float*)d_in[4];
    const float* wv = (const float*)d_in[5];
    const float* bv = (const float*)d_in[6];
    const float* wo = (const float*)d_in[7];
    const float* bo = (const float*)d_in[8];
    float* out = (float*)d_out;

    // ws layout (bf16 elems), ~200 MiB total.
    // Q, Kb, Vt must be contiguous in that order (MODE 2 epilogue).
    __bf16* ws  = (__bf16*)d_ws;
    __bf16* Xb  = ws;                   // 16,777,216 (phase 1; dead after QKV)
    __bf16* E   = ws;                   // 33,554,432 (phase 2, reuses Xb)
    __bf16* Q   = ws + 33554432;        // 16,777,216
    __bf16* Kb  = ws + 50331648;        // 16,777,216
    __bf16* Vt  = ws + 67108864;        // 16,777,216
    __bf16* Ctx = ws + 83886080;        // 16,777,216
    __bf16* WT  = ws + 100663296;       // 4,194,304
    float*  bc  = (float*)(ws + 104857600);  // 3072 fp32

    k_convert<<<8192, 256, 0, stream>>>(x, Xb);
    k_transpose_w<<<dim3(16, 16, 4), 256, 0, stream>>>(wq, wk, wv, wo, WT);
    k_bcat<<<12, 256, 0, stream>>>(bq, bk, bv, bc);

    // Fused QKV: [16384,3072] = Xb @ WT^T + bcat; writes Q, K, V^T
    // 128 row-tiles, 24 bn-tiles -> 3072 blocks; gy=128, rpx=16
    gemm_bt<2, true><<<3072, 256, 0, stream>>>(
        Xb, WT, bc, Q, 1024, 1024, 1024, 0, 128, 16, 1.0f, 0, 0, 0);

    // E[b] = Q[b] @ K[b]^T / 32   row_t=128 (16/z), bn=16 -> 2048 blocks
    gemm_bt<0, false><<<2048, 256, 0, stream>>>(
        Q, Kb, nullptr, E, 1024, 1024, 1024, 2048, 16, 16,
        0.03125f, 2097152, 2097152, 4194304);

    k_softmax<<<16384, 256, 0, stream>>>(E);

    // Ctx[b] = P[b] @ Vt[b]^T    row_t=128, bn=8 -> 1024 blocks
    gemm_bt<0, false><<<1024, 256, 0, stream>>>(
        E, Vt, nullptr, Ctx, 2048, 2048, 2048, 1024, 16, 16,
        1.0f, 4194304, 2097152, 2097152);

    // out = Ctx @ Wo^T + bo (fp32)  row_t=128, bn=8 -> 1024 blocks
    gemm_bt<1, true><<<1024, 256, 0, stream>>>(
        Ctx, WT + 3145728, bo, out, 1024, 1024, 1024, 1024, 128, 16,
        1.0f, 0, 0, 0);
}